// Round 5
// baseline (26.287 us; speedup 1.0000x reference)
//
#include <hip/hip_runtime.h>

// DepthLossForImgBEV: weighted BCE over (B,N,D,H,W) depth logits vs one-hot
// bucketized GT depth, reduced to a scalar mean * 3.0.
//
// B=2 N=6 D=112 H=64 W=176.  depth: (B,N*D,H,W) f32 (60.6 MB); depth_gt:
// (B,N,H,W) f32 (0.54 MB, cache-resident). Memory-bound; roofline ~9.7 us
// HBM (less with partial L3 residency: R3 showed FETCH ~31.5 MB).
//
// R4 lesson: 924 blocks @ 4/CU = exactly-resident grid -> no backfill, CUs
// with 4 blocks straggle over CUs with 3 (+11% tail). This round: DPC=8 ->
// 1848 smaller blocks, oversubscribed 1.8x so the scheduler backfills and
// the tail shrinks to ~1 block. LB(256,4) caps VGPR at 128 (no spill at ~70),
// 8 batched float4 loads per thread keep MLP deep enough.

namespace {

constexpr int B_ = 2, N_ = 6, D_ = 112, H_ = 64, W_ = 176;
constexpr int HW_   = H_ * W_;          // 11264
constexpr int NHWQ_ = HW_ / 4;          // 2816 float4 quads per image plane
constexpr int DPC_  = 8, NCH_ = 14;     // 14 d-chunks x 8 slices = 112
constexpr int NBN_  = B_ * N_;          // 12
constexpr long long TOT_ = (long long)NBN_ * D_ * HW_;   // 15,138,816
constexpr int NTHR_ = NBN_ * NCH_ * NHWQ_;               // 473,088
constexpr int NBLK_ = NTHR_ / 256;                       // 1848 blocks
constexpr float SCALE_ = (float)(3.0 / (double)TOT_);    // 3.0 / numel

// bce = min(softplus(+-x), 100) * w;  softplus(x) = relu(x) + log1p(exp(-|x|))
__device__ __forceinline__ float term(float x, float w, bool hit) {
    float c = __logf(1.0f + __expf(-fabsf(x)));          // shared log term
    float r = hit ? fmaxf(-x, 0.0f) : fmaxf(x, 0.0f);
    return w * fminf(c + r, 100.0f);
}

__device__ __forceinline__ int bucket(float g) {
    int i = (int)floorf((g - 2.0f) * 2.0f);   // (g - DBOUND0) / DBOUND2
    return i < 0 ? 0 : (i > D_ ? D_ : i);     // clip [0,D]; D never matches d
}

__global__ __launch_bounds__(256, 4) void depth_loss_part(
        const float* __restrict__ gt, const float* __restrict__ dp,
        float* __restrict__ part) {
    const int t    = blockIdx.x * 256 + threadIdx.x;
    const int hwq  = t % NHWQ_;           // quad within image plane
    const int rest = t / NHWQ_;
    const int ch   = rest % NCH_;         // which 8-slice d-chunk
    const int bn   = rest / NCH_;         // (b*N + n)
    const int hw   = hwq * 4;
    const int d0   = ch * DPC_;

    // gt quad first (bucket math depends on it), then batch all 8 slice loads
    const float4 g = *reinterpret_cast<const float4*>(gt + bn * HW_ + hw);
    const float* p = dp + ((bn * D_ + d0) * HW_ + hw);
    float4 xv[DPC_];
    #pragma unroll
    for (int i = 0; i < DPC_; ++i)
        xv[i] = *reinterpret_cast<const float4*>(p + (size_t)i * HW_);

    const float w0 = (g.x != 0.0f) ? 1.0f : 0.0f;
    const float w1 = (g.y != 0.0f) ? 1.0f : 0.0f;
    const float w2 = (g.z != 0.0f) ? 1.0f : 0.0f;
    const float w3 = (g.w != 0.0f) ? 1.0f : 0.0f;
    const int  i0 = bucket(g.x), i1 = bucket(g.y), i2 = bucket(g.z), i3 = bucket(g.w);

    float s = 0.0f;
    #pragma unroll
    for (int i = 0; i < DPC_; ++i) {
        const int d = d0 + i;
        s += term(xv[i].x, w0, d == i0);
        s += term(xv[i].y, w1, d == i1);
        s += term(xv[i].z, w2, d == i2);
        s += term(xv[i].w, w3, d == i3);
    }

    // block reduce -> one partial per block (overwrite, no init needed)
    #pragma unroll
    for (int off = 32; off > 0; off >>= 1) s += __shfl_down(s, off, 64);
    __shared__ float ls[4];
    if ((threadIdx.x & 63) == 0) ls[threadIdx.x >> 6] = s;
    __syncthreads();
    if (threadIdx.x == 0) {
        // NT store: push past this XCD's L2 so kernel2's cross-XCD reads are cheap
        __builtin_nontemporal_store((ls[0] + ls[1]) + (ls[2] + ls[3]),
                                    part + blockIdx.x);
    }
}

__global__ __launch_bounds__(256) void depth_loss_final(
        const float* __restrict__ part, float* __restrict__ out) {
    float s = 0.0f;
    for (int i = threadIdx.x; i < NBLK_; i += 256) s += part[i];
    #pragma unroll
    for (int off = 32; off > 0; off >>= 1) s += __shfl_down(s, off, 64);
    __shared__ float ls[4];
    if ((threadIdx.x & 63) == 0) ls[threadIdx.x >> 6] = s;
    __syncthreads();
    if (threadIdx.x == 0)
        out[0] = ((ls[0] + ls[1]) + (ls[2] + ls[3])) * SCALE_;
}

}  // namespace

extern "C" void kernel_launch(void* const* d_in, const int* in_sizes, int n_in,
                              void* d_out, int out_size, void* d_ws, size_t ws_size,
                              hipStream_t stream) {
    const float* gt = (const float*)d_in[0];   // depth_gt (B,N,H,W)
    const float* dp = (const float*)d_in[1];   // depth (B,N*D,H,W)
    float* part = (float*)d_ws;                // 1848 floats of scratch
    float* out  = (float*)d_out;
    depth_loss_part<<<NBLK_, 256, 0, stream>>>(gt, dp, part);
    depth_loss_final<<<1, 256, 0, stream>>>(part, out);
}

// Round 7
// 21.987 us; speedup vs baseline: 1.1956x; 1.1956x over previous
//
#include <hip/hip_runtime.h>

// DepthLossForImgBEV: weighted BCE over (B,N,D,H,W) depth logits vs one-hot
// bucketized GT depth, reduced to a scalar mean * 3.0.
//
// B=2 N=6 D=112 H=64 W=176.  depth: (B,N*D,H,W) f32 (60.6 MB); depth_gt:
// (B,N,H,W) f32 (0.54 MB, cache-resident). Memory-bound; k1 floor ~10 us.
//
// History: R4 two-kernel + xv[16]/256-thr blocks = 20.8 us (best). R6 coop
// fused = launch failure (unchecked hipLaunchCooperativeKernel error; coop
// abandoned). R7 theory: R4's k1 ran ~4.2 TB/s because 924 fat blocks at
// 3-4/CU residency leave a straggler round (+40-50%). Fix granularity only:
// 1-wave (64-thr) blocks, DPC=8 -> 7392 blocks, 28.9/CU, backfill smooths
// the tail to <4%. Wave-reduce partial (no LDS/syncthreads). LB(64,4)
// caps VGPR at 128 (xv[8]=32 + misc fits easily, no spill).

namespace {

constexpr int B_ = 2, N_ = 6, D_ = 112, H_ = 64, W_ = 176;
constexpr int HW_   = H_ * W_;          // 11264
constexpr int NHWQ_ = HW_ / 4;          // 2816 float4 quads per image plane (div by 64)
constexpr int DPC_  = 8, NCH_ = 14;     // 14 d-chunks x 8 slices = 112
constexpr int NBN_  = B_ * N_;          // 12
constexpr long long TOT_ = (long long)NBN_ * D_ * HW_;   // 15,138,816
constexpr int NCOL_  = NBN_ * NCH_ * NHWQ_;              // 473,088 thread-columns
constexpr int NBLK_  = NCOL_ / 64;                       // 7392 one-wave blocks
constexpr int NQUAD_ = NBLK_ / 4;                        // 1848 float4s of partials
constexpr float SCALE_ = (float)(3.0 / (double)TOT_);    // 3.0 / numel

// bce = min(softplus(+-x), 100) * w;  softplus(x) = relu(x) + log1p(exp(-|x|))
__device__ __forceinline__ float term(float x, float w, bool hit) {
    float c = __logf(1.0f + __expf(-fabsf(x)));          // shared log term
    float r = hit ? fmaxf(-x, 0.0f) : fmaxf(x, 0.0f);
    return w * fminf(c + r, 100.0f);
}

__device__ __forceinline__ int bucket(float g) {
    int i = (int)floorf((g - 2.0f) * 2.0f);   // (g - DBOUND0) / DBOUND2
    return i < 0 ? 0 : (i > D_ ? D_ : i);     // clip [0,D]; D never matches d
}

__global__ __launch_bounds__(64, 4) void depth_loss_part(
        const float* __restrict__ gt, const float* __restrict__ dp,
        float* __restrict__ part) {
    const int t    = blockIdx.x * 64 + threadIdx.x;
    const int hwq  = t % NHWQ_;           // quad within image plane
    const int rest = t / NHWQ_;           // constant per block (2816 % 64 == 0)
    const int ch   = rest % NCH_;         // which 8-slice d-chunk
    const int bn   = rest / NCH_;         // (b*N + n)
    const int hw   = hwq * 4;
    const int d0   = ch * DPC_;

    // gt quad first (bucket math needs it), then batch all 8 slice loads
    const float4 g = *reinterpret_cast<const float4*>(gt + bn * HW_ + hw);
    const float* p = dp + ((bn * D_ + d0) * HW_ + hw);
    float4 xv[DPC_];
    #pragma unroll
    for (int i = 0; i < DPC_; ++i)
        xv[i] = *reinterpret_cast<const float4*>(p + (size_t)i * HW_);

    const float w0 = (g.x != 0.0f) ? 1.0f : 0.0f;
    const float w1 = (g.y != 0.0f) ? 1.0f : 0.0f;
    const float w2 = (g.z != 0.0f) ? 1.0f : 0.0f;
    const float w3 = (g.w != 0.0f) ? 1.0f : 0.0f;
    const int  i0 = bucket(g.x), i1 = bucket(g.y), i2 = bucket(g.z), i3 = bucket(g.w);

    float s = 0.0f;
    #pragma unroll
    for (int i = 0; i < DPC_; ++i) {
        const int d = d0 + i;
        s += term(xv[i].x, w0, d == i0);
        s += term(xv[i].y, w1, d == i1);
        s += term(xv[i].z, w2, d == i2);
        s += term(xv[i].w, w3, d == i3);
    }

    // single-wave reduce -> one partial per block (no LDS, no barrier)
    #pragma unroll
    for (int off = 32; off > 0; off >>= 1) s += __shfl_down(s, off, 64);
    if (threadIdx.x == 0)
        part[blockIdx.x] = s;
}

__global__ __launch_bounds__(256) void depth_loss_final(
        const float* __restrict__ part, float* __restrict__ out) {
    float s = 0.0f;
    for (int i = threadIdx.x; i < NQUAD_; i += 256) {    // 1848 quads, ~7.2/thread
        float4 q = reinterpret_cast<const float4*>(part)[i];
        s += (q.x + q.y) + (q.z + q.w);
    }
    #pragma unroll
    for (int off = 32; off > 0; off >>= 1) s += __shfl_down(s, off, 64);
    __shared__ float ls[4];
    if ((threadIdx.x & 63) == 0) ls[threadIdx.x >> 6] = s;
    __syncthreads();
    if (threadIdx.x == 0)
        out[0] = ((ls[0] + ls[1]) + (ls[2] + ls[3])) * SCALE_;
}

}  // namespace

extern "C" void kernel_launch(void* const* d_in, const int* in_sizes, int n_in,
                              void* d_out, int out_size, void* d_ws, size_t ws_size,
                              hipStream_t stream) {
    const float* gt = (const float*)d_in[0];   // depth_gt (B,N,H,W)
    const float* dp = (const float*)d_in[1];   // depth (B,N*D,H,W)
    float* part = (float*)d_ws;                // 7392 floats of scratch
    float* out  = (float*)d_out;
    depth_loss_part<<<NBLK_, 64, 0, stream>>>(gt, dp, part);
    depth_loss_final<<<1, 256, 0, stream>>>(part, out);
}